// Round 5
// baseline (818.246 us; speedup 1.0000x reference)
//
#include <hip/hip_runtime.h>

// Problem constants
#define NC   8192
#define NEFF 8192
#define DIN  256
#define DOUT 128
#define SCALE 0.08838834764831843f  // 1/sqrt(128)

typedef float  f32x4  __attribute__((ext_vector_type(4)));
typedef short  s16x8  __attribute__((ext_vector_type(8)));
typedef unsigned long long u64;

// RNE float -> bf16 (as short)
__device__ __forceinline__ short f2bf(float f) {
    unsigned int u = __builtin_bit_cast(unsigned int, f);
    u += 0x7FFFu + ((u >> 16) & 1u);
    return (short)(u >> 16);
}

__device__ __forceinline__ s16x8 ld8(const short* p) {
    return *(const s16x8*)__builtin_assume_aligned(p, 16);
}

__device__ __forceinline__ int geti(int4 v, int i) {
    switch (i & 3) {
        case 0: return v.x;
        case 1: return v.y;
        case 2: return v.z;
        default: return v.w;
    }
}

// ---------------------------------------------------------------------------
// Fragment-major layouts (all bf16, s16x8 = one lane's A/B fragment):
//  Qf[tile(512)][kc(4)][lane(64)] : Q[tile*16+ln16][kc*32+quad*8+j] * SCALE
//  Kf[tile(512)][kc(4)][lane(64)] : K[tile*16+ln16][kc*32+quad*8+j]
//  Vf[ct(64)][nt2(8)][ksub(4)][lane(64)] : V[ct*128+ksub*32+quad*8+j][nt2*16+ln16]
//
// PIPELINE (this round): S = QK^T computed ONCE.
//  expS_kernel : mask (raw, 268MB) + Qf/Kf -> outW := exp(S) or 0 (fp32, unnorm)
//                + lsum row sums.  Pure streaming read+write, one regime.
//  normpv_kernel: outW *= 1/lsum (in place, bit-identical to expf*rl), and
//                fused O = W @ V from registers. No LDS, no mask, no recompute.
// pack/bitmap/stats/attn kernels deleted.
// ---------------------------------------------------------------------------

// ---------------------------------------------------------------------------
// Kernel 1: QKV projections. grid(128, 3).
// ---------------------------------------------------------------------------
__global__ __launch_bounds__(256, 2) void qkv_kernel(
    const float* __restrict__ embc, const float* __restrict__ embe,
    const float* __restrict__ Wq, const float* __restrict__ bq,
    const float* __restrict__ Wk, const float* __restrict__ bk,
    const float* __restrict__ Wv, const float* __restrict__ bv,
    short* __restrict__ Qf, short* __restrict__ Kf, short* __restrict__ Vf)
{
    const int mat = blockIdx.y;
    const float* src  = (mat == 0) ? embc : embe;
    const float* W    = (mat == 0) ? Wq : (mat == 1 ? Wk : Wv);
    const float* bias = (mat == 0) ? bq : (mat == 1 ? bk : bv);

    __shared__ short wt[DOUT][136];       // W^T staging (half-K at a time)
    __shared__ short tbuf[4][16][132];    // per-wave transpose buffer (Q/K path)
    __shared__ short tbufV[128][68];      // block-wide transpose buffer (V path)

    const int tid  = threadIdx.x;
    const int wave = tid >> 6, lane = tid & 63;
    const int quad = lane >> 4, ln16 = lane & 15;
    const int rowbase = blockIdx.x * 64;
    const int arow = rowbase + wave * 16 + ln16;   // A-fragment row

    f32x4 acc[8];
#pragma unroll
    for (int i = 0; i < 8; i++) acc[i] = (f32x4){0.f, 0.f, 0.f, 0.f};

    for (int h = 0; h < 2; h++) {
        __syncthreads();   // WAR vs previous half's reads
        {   // stage W[h*128 .. +127][0..127] transposed into wt (bf16)
            const int n0 = (tid & 31) * 4;
            const int kb = tid >> 5;               // 0..7
#pragma unroll
            for (int i = 0; i < 16; i++) {
                const int k = kb + i * 8;          // 0..127 (local)
                const float4 w4 = *(const float4*)(W + (size_t)(h * 128 + k) * DOUT + n0);
                wt[n0 + 0][k] = f2bf(w4.x);
                wt[n0 + 1][k] = f2bf(w4.y);
                wt[n0 + 2][k] = f2bf(w4.z);
                wt[n0 + 3][k] = f2bf(w4.w);
            }
        }
        __syncthreads();

        s16x8 afr[4];
#pragma unroll
        for (int kc = 0; kc < 4; kc++) {
            const float* ap = src + (size_t)arow * DIN + h * 128 + kc * 32 + quad * 8;
            const float4 a0 = *(const float4*)ap;
            const float4 a1 = *(const float4*)(ap + 4);
            s16x8 a;
            a[0] = f2bf(a0.x); a[1] = f2bf(a0.y); a[2] = f2bf(a0.z); a[3] = f2bf(a0.w);
            a[4] = f2bf(a1.x); a[5] = f2bf(a1.y); a[6] = f2bf(a1.z); a[7] = f2bf(a1.w);
            afr[kc] = a;
        }
#pragma unroll
        for (int nt = 0; nt < 8; nt++) {
#pragma unroll
            for (int kc = 0; kc < 4; kc++) {
                const s16x8 b = ld8(&wt[nt * 16 + ln16][kc * 32 + quad * 8]);
                acc[nt] = __builtin_amdgcn_mfma_f32_16x16x32_bf16(afr[kc], b, acc[nt], 0, 0, 0);
            }
        }
    }

    if (mat < 2) {
        short* dst = (mat == 0) ? Qf : Kf;
        const float sc = (mat == 0) ? SCALE : 1.0f;
        // C-layout -> tbuf (per-wave; wave-internal ordering only)
#pragma unroll
        for (int nt = 0; nt < 8; nt++) {
            const float bb = bias[nt * 16 + ln16];
#pragma unroll
            for (int r = 0; r < 4; r++)
                tbuf[wave][quad * 4 + r][nt * 16 + ln16] = f2bf((acc[nt][r] + bb) * sc);
        }
        const int tile = blockIdx.x * 4 + wave;
#pragma unroll
        for (int kc = 0; kc < 4; kc++) {
            const s16x8 fr = ld8(&tbuf[wave][ln16][kc * 32 + quad * 8]);
            *(s16x8*)(dst + ((size_t)(tile * 4 + kc) * 64 + lane) * 8) = fr;
        }
    } else {
        // V: transpose to [feat][vcol] then emit PV B-fragments
#pragma unroll
        for (int nt = 0; nt < 8; nt++) {
            const float bb = bias[nt * 16 + ln16];
#pragma unroll
            for (int r = 0; r < 4; r++)
                tbufV[nt * 16 + ln16][wave * 16 + quad * 4 + r] = f2bf(acc[nt][r] + bb);
        }
        __syncthreads();   // cross-wave reads of tbufV
        const int ct = blockIdx.x >> 1;
        const int ksub0 = (blockIdx.x & 1) * 2;
        const int ks = wave & 1;
#pragma unroll
        for (int t = 0; t < 4; t++) {
            const int nt2 = (wave >> 1) * 4 + t;
            const s16x8 fr = ld8(&tbufV[nt2 * 16 + ln16][ks * 32 + quad * 8]);
            *(s16x8*)(Vf + ((size_t)((ct * 8 + nt2) * 4 + ksub0 + ks) * 64 + lane) * 8) = fr;
        }
    }
}

// ---------------------------------------------------------------------------
// Kernel 2: expS. Computes swapped S^T tiles ONCE, writes unnormalized
// exp(S) (or 0 where masked) as fp32 into outW, accumulates row sums.
// Reads raw mask directly (268 MB) -- pack kernel + bitmap eliminated.
// grid(64, 32): blockIdx.x = 128-row block (4 waves x 32 rows),
// blockIdx.y = 256-col strip (2 iters of 128 cols).
// Swapped layout: lane(quad,ln16) reg r = S[ln16(+rs*16)][nt*16+quad*4+r]
// -> mask int4 load + float4 store per (nt,rs), both 16B coalesced.
// NOTE: outW = expf(c) stored fp32; normpv multiplies by rl later with the
// exact same operands -> final outW bits identical to fused expf(c)*rl.
// ---------------------------------------------------------------------------
__global__ __launch_bounds__(256, 4) void expS_kernel(
    const int* __restrict__ mask, const short* __restrict__ Qf,
    const short* __restrict__ Kf, float* __restrict__ lsum,
    float* __restrict__ outW)
{
    const int bx = blockIdx.x, strip = blockIdx.y;
    const int tid  = threadIdx.x;
    const int wave = tid >> 6, lane = tid & 63;
    const int quad = lane >> 4, ln16 = lane & 15;
    const int rowbase = bx * 128 + wave * 32;
    const int t0 = rowbase >> 4;

    s16x8 aq[2][4];
#pragma unroll
    for (int rs = 0; rs < 2; rs++)
#pragma unroll
        for (int kc = 0; kc < 4; kc++)
            aq[rs][kc] = ld8(Qf + ((size_t)((t0 + rs) * 4 + kc) * 64 + lane) * 8);

    float lp[2] = {0.f, 0.f};

    for (int it = 0; it < 2; it++) {
        const int cb = strip * 256 + it * 128;

#pragma unroll
        for (int nt = 0; nt < 8; nt++) {
            s16x8 bq[4];
#pragma unroll
            for (int kc = 0; kc < 4; kc++)
                bq[kc] = ld8(Kf + ((size_t)(((cb >> 4) + nt) * 4 + kc) * 64 + lane) * 8);
            f32x4 c0 = (f32x4){0.f, 0.f, 0.f, 0.f};
            f32x4 c1 = (f32x4){0.f, 0.f, 0.f, 0.f};
#pragma unroll
            for (int kc = 0; kc < 4; kc++) {
                c0 = __builtin_amdgcn_mfma_f32_16x16x32_bf16(bq[kc], aq[0][kc], c0, 0, 0, 0);
                c1 = __builtin_amdgcn_mfma_f32_16x16x32_bf16(bq[kc], aq[1][kc], c1, 0, 0, 0);
            }
            // lane: S[q = rowbase+rs*16+ln16][cb + nt*16 + quad*4 + r]
#pragma unroll
            for (int rs = 0; rs < 2; rs++) {
                const int row = rowbase + rs * 16 + ln16;
                const size_t base = (size_t)row * NEFF + cb + nt * 16 + quad * 4;
                const int4 mv = *(const int4*)(mask + base);
                float wv[4];
#pragma unroll
                for (int r = 0; r < 4; r++) {
                    const float cv = rs ? c1[r] : c0[r];
                    const float e = (geti(mv, r) != 0) ? __expf(cv) : 0.0f;
                    wv[r] = e;
                    lp[rs] += e;
                }
                float4 w4; w4.x = wv[0]; w4.y = wv[1]; w4.z = wv[2]; w4.w = wv[3];
                *(float4*)(outW + base) = w4;
            }
        }
    }

    // reduce across quads (lanes with equal ln16 hold the same row)
#pragma unroll
    for (int rs = 0; rs < 2; rs++) {
        float v = lp[rs];
        v += __shfl_xor(v, 16);
        v += __shfl_xor(v, 32);
        if (quad == 0)
            atomicAdd(&lsum[rowbase + rs * 16 + ln16], v);
    }
}

// ---------------------------------------------------------------------------
// Kernel 3: normpv. In-place normalize outW (wv = expS * rl, bit-identical
// to the previous fused expf*rl) and fused O = W @ V from registers.
// grid(128, 16): blockIdx.x = 64-row block (4 waves x 16 rows),
// blockIdx.y = 512-col K strip (4 iters of 128 cols).
// No LDS, no mask, shallow chains (ld -> mul -> cvt -> mfma -> st).
// 16 rows/wave keeps VGPR ~90 -> (256,4) fits w/o spill; 2048 blocks =
// exactly 8/CU in 2 clean rounds (no 3-resident tail like (256,3)).
// Each block reads+writes only its own (row,K) outW region -> no race.
// ---------------------------------------------------------------------------
__global__ __launch_bounds__(256, 4) void normpv_kernel(
    const short* __restrict__ Vf, const float* __restrict__ lsum,
    float* __restrict__ outO, float* __restrict__ outW)
{
    const int bx = blockIdx.x, strip = blockIdx.y;
    const int tid  = threadIdx.x;
    const int wave = tid >> 6, lane = tid & 63;
    const int quad = lane >> 4, ln16 = lane & 15;
    const int rowbase = bx * 64 + wave * 16;
    const int row = rowbase + ln16;           // A-fragment row (this lane)

    const float rl = 1.0f / lsum[row];

    f32x4 o[8];
#pragma unroll
    for (int i = 0; i < 8; i++) o[i] = (f32x4){0.f, 0.f, 0.f, 0.f};

    for (int it = 0; it < 4; it++) {
        const int cb = strip * 512 + it * 128;
        const int ct = cb >> 7;               // global 128-k tile index

#pragma unroll
        for (int ks = 0; ks < 4; ks++) {
            float* wp = outW + (size_t)row * NEFF + cb + ks * 32 + quad * 8;
            float4 w0 = *(const float4*)wp;
            float4 w1 = *(const float4*)(wp + 4);
            w0.x *= rl; w0.y *= rl; w0.z *= rl; w0.w *= rl;
            w1.x *= rl; w1.y *= rl; w1.z *= rl; w1.w *= rl;
            *(float4*)wp = w0;
            *(float4*)(wp + 4) = w1;
            s16x8 aw;
            aw[0] = f2bf(w0.x); aw[1] = f2bf(w0.y);
            aw[2] = f2bf(w0.z); aw[3] = f2bf(w0.w);
            aw[4] = f2bf(w1.x); aw[5] = f2bf(w1.y);
            aw[6] = f2bf(w1.z); aw[7] = f2bf(w1.w);
#pragma unroll
            for (int nt2 = 0; nt2 < 8; nt2++) {
                const s16x8 bv = ld8(Vf + ((size_t)((ct * 8 + nt2) * 4 + ks) * 64 + lane) * 8);
                o[nt2] = __builtin_amdgcn_mfma_f32_16x16x32_bf16(aw, bv, o[nt2], 0, 0, 0);
            }
        }
    }

    // O strip-partials -> global atomics (outO pre-zeroed)
#pragma unroll
    for (int nt2 = 0; nt2 < 8; nt2++)
#pragma unroll
        for (int r = 0; r < 4; r++) {
            const int orow = rowbase + quad * 4 + r;
            atomicAdd(&outO[(size_t)orow * DOUT + nt2 * 16 + ln16], o[nt2][r]);
        }
}

// ---------------------------------------------------------------------------
extern "C" void kernel_launch(void* const* d_in, const int* in_sizes, int n_in,
                              void* d_out, int out_size, void* d_ws, size_t ws_size,
                              hipStream_t stream) {
    (void)in_sizes; (void)n_in; (void)out_size; (void)ws_size;

    const float* embc = (const float*)d_in[0];
    const float* embe = (const float*)d_in[1];
    const int*   mask = (const int*)d_in[2];
    const float* Wq = (const float*)d_in[3];
    const float* bq = (const float*)d_in[4];
    const float* Wk = (const float*)d_in[5];
    const float* bk = (const float*)d_in[6];
    const float* Wv = (const float*)d_in[7];
    const float* bv = (const float*)d_in[8];

    char* ws = (char*)d_ws;
    short* Qf = (short*)(ws);                        // 2 MB  frag-major, pre-scaled
    short* Kf = (short*)(ws + (2u << 20));           // 2 MB  frag-major
    short* Vf = (short*)(ws + (4u << 20));           // 2 MB  frag-major (PV B)
    float* lsum = (float*)(ws + (6u << 20));         // 32 KB

    float* outO = (float*)d_out;                     // [8192,128]
    float* outW = outO + (size_t)NC * DOUT;          // [8192,8192]

    hipMemsetAsync(lsum, 0, NC * sizeof(float), stream);
    hipMemsetAsync(outO, 0, (size_t)NC * DOUT * sizeof(float), stream);

    qkv_kernel<<<dim3(128, 3), 256, 0, stream>>>(embc, embe, Wq, bq, Wk, bk, Wv, bv,
                                                 Qf, Kf, Vf);
    expS_kernel<<<dim3(64, 32), 256, 0, stream>>>(mask, Qf, Kf, lsum, outW);
    normpv_kernel<<<dim3(128, 16), 256, 0, stream>>>(Vf, lsum, outO, outW);
}

// Round 6
// 685.589 us; speedup vs baseline: 1.1935x; 1.1935x over previous
//
#include <hip/hip_runtime.h>

// Problem constants
#define NC   8192
#define NEFF 8192
#define DIN  256
#define DOUT 128
#define SCALE 0.08838834764831843f  // 1/sqrt(128)

typedef float  f32x4  __attribute__((ext_vector_type(4)));
typedef short  s16x8  __attribute__((ext_vector_type(8)));
typedef short  s16x4  __attribute__((ext_vector_type(4)));
typedef unsigned long long u64;

// RNE float -> bf16 (as short)
__device__ __forceinline__ short f2bf(float f) {
    unsigned int u = __builtin_bit_cast(unsigned int, f);
    u += 0x7FFFu + ((u >> 16) & 1u);
    return (short)(u >> 16);
}

__device__ __forceinline__ s16x8 ld8(const short* p) {
    return *(const s16x8*)__builtin_assume_aligned(p, 16);
}

__device__ __forceinline__ unsigned getdw(int4 v, int i) {
    switch (i & 3) {
        case 0: return (unsigned)v.x;
        case 1: return (unsigned)v.y;
        case 2: return (unsigned)v.z;
        default: return (unsigned)v.w;
    }
}

// ---------------------------------------------------------------------------
// Fragment-major layouts (all bf16, s16x8 = one lane's A/B fragment):
//  Qf[tile(512)][kc(4)][lane(64)] : Q[tile*16+ln16][kc*32+quad*8+j] * SCALE
//  Kf[tile(512)][kc(4)][lane(64)] : K[tile*16+ln16][kc*32+quad*8+j]
//  Vf[ct(64)][nt2(8)][ksub(4)][lane(64)] : V[ct*128+ksub*32+quad*8+j][nt2*16+ln16]
// bm bit layout: bit c%32 of dword bm32[row*256 + c/32]  <=>  mask[row][c]!=0
//
// PIPELINE (best-measured combination):
//  pack  (R0): mask 268MB -> 8MB bitmap, pure stream.
//  qkv   (R0): QKV projections -> fragments.
//  stats (R0 exact): bitmap+fragments -> row sums. R4's swapped/regridded
//        stats regressed ~100us (bounds(256,5) register squeeze) - reverted.
//  attn  (R4 exact, measured 190us): swapped S^T, 32 rows/wave, dwordx4 outW.
// R5's expS/normpv split (store+reload expS through DRAM) measured 262us for
// normpv alone at VGPR=36 (no prefetch depth) - recompute beats reload.
// ---------------------------------------------------------------------------

// ---------------------------------------------------------------------------
// Kernel 0: pack mask (268 MB int32) -> 8 MB bitmap. Pure streaming read,
// 8 independent loads in flight per wave, 8192 blocks (huge TLP).
// ---------------------------------------------------------------------------
__global__ __launch_bounds__(256) void pack_kernel(
    const int* __restrict__ mask, u64* __restrict__ bm)
{
    const size_t stride = (size_t)gridDim.x * 256;     // multiple of 64
    const size_t i0 = (size_t)blockIdx.x * 256 + threadIdx.x;
    const bool lead = (threadIdx.x & 63) == 0;
    for (size_t i = i0; i < (size_t)NC * NEFF; i += 8 * stride) {
        int m[8];
#pragma unroll
        for (int j = 0; j < 8; j++) m[j] = mask[i + j * stride];
        u64 b[8];
#pragma unroll
        for (int j = 0; j < 8; j++) b[j] = __ballot(m[j] != 0);
        if (lead) {
#pragma unroll
            for (int j = 0; j < 8; j++) bm[(i + j * stride) >> 6] = b[j];
        }
    }
}

// ---------------------------------------------------------------------------
// Kernel 1: QKV projections. grid(128, 3).
// ---------------------------------------------------------------------------
__global__ __launch_bounds__(256, 2) void qkv_kernel(
    const float* __restrict__ embc, const float* __restrict__ embe,
    const float* __restrict__ Wq, const float* __restrict__ bq,
    const float* __restrict__ Wk, const float* __restrict__ bk,
    const float* __restrict__ Wv, const float* __restrict__ bv,
    short* __restrict__ Qf, short* __restrict__ Kf, short* __restrict__ Vf)
{
    const int mat = blockIdx.y;
    const float* src  = (mat == 0) ? embc : embe;
    const float* W    = (mat == 0) ? Wq : (mat == 1 ? Wk : Wv);
    const float* bias = (mat == 0) ? bq : (mat == 1 ? bk : bv);

    __shared__ short wt[DOUT][136];       // W^T staging (half-K at a time)
    __shared__ short tbuf[4][16][132];    // per-wave transpose buffer (Q/K path)
    __shared__ short tbufV[128][68];      // block-wide transpose buffer (V path)

    const int tid  = threadIdx.x;
    const int wave = tid >> 6, lane = tid & 63;
    const int quad = lane >> 4, ln16 = lane & 15;
    const int rowbase = blockIdx.x * 64;
    const int arow = rowbase + wave * 16 + ln16;   // A-fragment row

    f32x4 acc[8];
#pragma unroll
    for (int i = 0; i < 8; i++) acc[i] = (f32x4){0.f, 0.f, 0.f, 0.f};

    for (int h = 0; h < 2; h++) {
        __syncthreads();   // WAR vs previous half's reads
        {   // stage W[h*128 .. +127][0..127] transposed into wt (bf16)
            const int n0 = (tid & 31) * 4;
            const int kb = tid >> 5;               // 0..7
#pragma unroll
            for (int i = 0; i < 16; i++) {
                const int k = kb + i * 8;          // 0..127 (local)
                const float4 w4 = *(const float4*)(W + (size_t)(h * 128 + k) * DOUT + n0);
                wt[n0 + 0][k] = f2bf(w4.x);
                wt[n0 + 1][k] = f2bf(w4.y);
                wt[n0 + 2][k] = f2bf(w4.z);
                wt[n0 + 3][k] = f2bf(w4.w);
            }
        }
        __syncthreads();

        s16x8 afr[4];
#pragma unroll
        for (int kc = 0; kc < 4; kc++) {
            const float* ap = src + (size_t)arow * DIN + h * 128 + kc * 32 + quad * 8;
            const float4 a0 = *(const float4*)ap;
            const float4 a1 = *(const float4*)(ap + 4);
            s16x8 a;
            a[0] = f2bf(a0.x); a[1] = f2bf(a0.y); a[2] = f2bf(a0.z); a[3] = f2bf(a0.w);
            a[4] = f2bf(a1.x); a[5] = f2bf(a1.y); a[6] = f2bf(a1.z); a[7] = f2bf(a1.w);
            afr[kc] = a;
        }
#pragma unroll
        for (int nt = 0; nt < 8; nt++) {
#pragma unroll
            for (int kc = 0; kc < 4; kc++) {
                const s16x8 b = ld8(&wt[nt * 16 + ln16][kc * 32 + quad * 8]);
                acc[nt] = __builtin_amdgcn_mfma_f32_16x16x32_bf16(afr[kc], b, acc[nt], 0, 0, 0);
            }
        }
    }

    if (mat < 2) {
        short* dst = (mat == 0) ? Qf : Kf;
        const float sc = (mat == 0) ? SCALE : 1.0f;
        // C-layout -> tbuf (per-wave; wave-internal ordering only)
#pragma unroll
        for (int nt = 0; nt < 8; nt++) {
            const float bb = bias[nt * 16 + ln16];
#pragma unroll
            for (int r = 0; r < 4; r++)
                tbuf[wave][quad * 4 + r][nt * 16 + ln16] = f2bf((acc[nt][r] + bb) * sc);
        }
        const int tile = blockIdx.x * 4 + wave;
#pragma unroll
        for (int kc = 0; kc < 4; kc++) {
            const s16x8 fr = ld8(&tbuf[wave][ln16][kc * 32 + quad * 8]);
            *(s16x8*)(dst + ((size_t)(tile * 4 + kc) * 64 + lane) * 8) = fr;
        }
    } else {
        // V: transpose to [feat][vcol] then emit PV B-fragments
#pragma unroll
        for (int nt = 0; nt < 8; nt++) {
            const float bb = bias[nt * 16 + ln16];
#pragma unroll
            for (int r = 0; r < 4; r++)
                tbufV[nt * 16 + ln16][wave * 16 + quad * 4 + r] = f2bf(acc[nt][r] + bb);
        }
        __syncthreads();   // cross-wave reads of tbufV
        const int ct = blockIdx.x >> 1;
        const int ksub0 = (blockIdx.x & 1) * 2;
        const int ks = wave & 1;
#pragma unroll
        for (int t = 0; t < 4; t++) {
            const int nt2 = (wave >> 1) * 4 + t;
            const s16x8 fr = ld8(&tbufV[nt2 * 16 + ln16][ks * 32 + quad * 8]);
            *(s16x8*)(Vf + ((size_t)((ct * 8 + nt2) * 4 + ksub0 + ks) * 64 + lane) * 8) = fr;
        }
    }
}

// ---------------------------------------------------------------------------
// Kernel 2: per-row sum of exp(masked scores) from bitmap + fragments.
// R0 EXACT CONFIG (never in top-5 there; R4's swap/regrid regressed ~100us).
// grid(64, 16): blockIdx.x = 128-row block (4 waves x 32 rows),
// blockIdx.y = 512-col strip (4 iters of 128 cols). No LDS.
// ---------------------------------------------------------------------------
__global__ __launch_bounds__(256, 4) void stats_kernel(
    const unsigned int* __restrict__ bm, const short* __restrict__ Qf,
    const short* __restrict__ Kf, float* __restrict__ lsum)
{
    const int bx = blockIdx.x, strip = blockIdx.y;
    const int tid  = threadIdx.x;
    const int wave = tid >> 6, lane = tid & 63;
    const int quad = lane >> 4, ln16 = lane & 15;
    const int rowbase = bx * 128 + wave * 32;
    const int t0 = rowbase >> 4;

    s16x8 aq[2][4];
#pragma unroll
    for (int rs = 0; rs < 2; rs++)
#pragma unroll
        for (int kc = 0; kc < 4; kc++)
            aq[rs][kc] = ld8(Qf + ((size_t)((t0 + rs) * 4 + kc) * 64 + lane) * 8);

    float lp[8] = {0.f, 0.f, 0.f, 0.f, 0.f, 0.f, 0.f, 0.f};

    for (int it = 0; it < 4; it++) {
        const int cb = strip * 512 + it * 128;

        int4 bmv[2][4];
#pragma unroll
        for (int rs = 0; rs < 2; rs++)
#pragma unroll
            for (int r = 0; r < 4; r++)
                bmv[rs][r] = *(const int4*)(bm + (size_t)(rowbase + rs * 16 + quad * 4 + r) * 256 + (cb >> 5));

#pragma unroll
        for (int nt = 0; nt < 8; nt++) {
            s16x8 bq[4];
#pragma unroll
            for (int kc = 0; kc < 4; kc++)
                bq[kc] = ld8(Kf + ((size_t)(((cb >> 4) + nt) * 4 + kc) * 64 + lane) * 8);
            f32x4 c0 = (f32x4){0.f, 0.f, 0.f, 0.f};
            f32x4 c1 = (f32x4){0.f, 0.f, 0.f, 0.f};
#pragma unroll
            for (int kc = 0; kc < 4; kc++) {
                c0 = __builtin_amdgcn_mfma_f32_16x16x32_bf16(aq[0][kc], bq[kc], c0, 0, 0, 0);
                c1 = __builtin_amdgcn_mfma_f32_16x16x32_bf16(aq[1][kc], bq[kc], c1, 0, 0, 0);
            }
#pragma unroll
            for (int rs = 0; rs < 2; rs++)
#pragma unroll
                for (int r = 0; r < 4; r++) {
                    const unsigned d = getdw(bmv[rs][r], nt >> 1);
                    const float cv = rs ? c1[r] : c0[r];
                    if ((d >> ((nt & 1) * 16 + ln16)) & 1u)
                        lp[rs * 4 + r] += __expf(cv);
                }
        }
    }

#pragma unroll
    for (int i = 0; i < 8; i++) {
        float v = lp[i];
        v += __shfl_xor(v, 1); v += __shfl_xor(v, 2);
        v += __shfl_xor(v, 4); v += __shfl_xor(v, 8);
        if (ln16 == 0)
            atomicAdd(&lsum[rowbase + (i >> 2) * 16 + quad * 4 + (i & 3)], v);
    }
}

// ---------------------------------------------------------------------------
// Kernel 3: recompute S (swapped), write W, fused O = W @ V.
// R4 EXACT CONFIG (measured 190us, VGPR 84, FETCH 34MB).
// grid(64, 32): blockIdx.x = 128-row block (4 waves x 32 rows),
// blockIdx.y = 256-col strip (2 iters of 128 cols).
// Swapped S^T layout: outW as dwordx4, wlds as ds_write_b64, bmv int4/rowset.
// DO NOT force higher min-waves: (256,8) => VGPR=32 => 700MB spill (R2).
// ---------------------------------------------------------------------------
__global__ __launch_bounds__(256, 3) void attn_kernel(
    const short* __restrict__ Qf, const short* __restrict__ Kf,
    const short* __restrict__ Vf, const float* __restrict__ lsum,
    const unsigned int* __restrict__ bm,
    float* __restrict__ outO, float* __restrict__ outW)
{
    __shared__ short wlds[4][32][132];   // per-wave 32x128 W tile (bf16), 33.8 KB

    const int bx = blockIdx.x, strip = blockIdx.y;
    const int tid  = threadIdx.x;
    const int wave = tid >> 6, lane = tid & 63;
    const int quad = lane >> 4, ln16 = lane & 15;
    const int rowbase = bx * 128 + wave * 32;
    const int t0 = rowbase >> 4;

    s16x8 aq[2][4];
#pragma unroll
    for (int rs = 0; rs < 2; rs++)
#pragma unroll
        for (int kc = 0; kc < 4; kc++)
            aq[rs][kc] = ld8(Qf + ((size_t)((t0 + rs) * 4 + kc) * 64 + lane) * 8);

    float rl[2];
#pragma unroll
    for (int rs = 0; rs < 2; rs++)
        rl[rs] = 1.0f / lsum[rowbase + rs * 16 + ln16];

    f32x4 o[2][8];
#pragma unroll
    for (int rs = 0; rs < 2; rs++)
#pragma unroll
        for (int i = 0; i < 8; i++) o[rs][i] = (f32x4){0.f, 0.f, 0.f, 0.f};

    for (int it = 0; it < 2; it++) {
        const int cb = strip * 256 + it * 128;

        int4 bmv[2];
#pragma unroll
        for (int rs = 0; rs < 2; rs++)
            bmv[rs] = *(const int4*)(bm + (size_t)(rowbase + rs * 16 + ln16) * 256 + (cb >> 5));

#pragma unroll
        for (int nt = 0; nt < 8; nt++) {
            s16x8 bq[4];
#pragma unroll
            for (int kc = 0; kc < 4; kc++)
                bq[kc] = ld8(Kf + ((size_t)(((cb >> 4) + nt) * 4 + kc) * 64 + lane) * 8);
            f32x4 c0 = (f32x4){0.f, 0.f, 0.f, 0.f};
            f32x4 c1 = (f32x4){0.f, 0.f, 0.f, 0.f};
#pragma unroll
            for (int kc = 0; kc < 4; kc++) {
                c0 = __builtin_amdgcn_mfma_f32_16x16x32_bf16(bq[kc], aq[0][kc], c0, 0, 0, 0);
                c1 = __builtin_amdgcn_mfma_f32_16x16x32_bf16(bq[kc], aq[1][kc], c1, 0, 0, 0);
            }
            // lane: S[q = rowbase+rs*16+ln16][cb + nt*16 + quad*4 + r]
#pragma unroll
            for (int rs = 0; rs < 2; rs++) {
                const unsigned d = getdw(bmv[rs], nt >> 1);
                float wv[4];
#pragma unroll
                for (int r = 0; r < 4; r++) {
                    const float cv = rs ? c1[r] : c0[r];
                    wv[r] = ((d >> ((nt & 1) * 16 + quad * 4 + r)) & 1u)
                                ? __expf(cv) * rl[rs] : 0.0f;
                }
                const int row = rowbase + rs * 16 + ln16;
                float4 w4; w4.x = wv[0]; w4.y = wv[1]; w4.z = wv[2]; w4.w = wv[3];
                *(float4*)(outW + (size_t)row * NEFF + cb + nt * 16 + quad * 4) = w4;
                s16x4 p4;
                p4[0] = f2bf(wv[0]); p4[1] = f2bf(wv[1]);
                p4[2] = f2bf(wv[2]); p4[3] = f2bf(wv[3]);
                *(s16x4*)__builtin_assume_aligned(
                    &wlds[wave][rs * 16 + ln16][nt * 16 + quad * 4], 8) = p4;
            }
        }

        // PV: A from per-wave LDS (wave-internal ordering only; the compiler
        // inserts the lgkmcnt waits), B = Vf coalesced fragment stream shared
        // by both row-sets.
#pragma unroll
        for (int ks = 0; ks < 4; ks++) {
            const s16x8 aw0 = ld8(&wlds[wave][ln16][ks * 32 + quad * 8]);
            const s16x8 aw1 = ld8(&wlds[wave][16 + ln16][ks * 32 + quad * 8]);
#pragma unroll
            for (int nt2 = 0; nt2 < 8; nt2++) {
                const s16x8 bv = ld8(Vf + ((size_t)(((cb >> 7) * 8 + nt2) * 4 + ks) * 64 + lane) * 8);
                o[0][nt2] = __builtin_amdgcn_mfma_f32_16x16x32_bf16(aw0, bv, o[0][nt2], 0, 0, 0);
                o[1][nt2] = __builtin_amdgcn_mfma_f32_16x16x32_bf16(aw1, bv, o[1][nt2], 0, 0, 0);
            }
        }
    }

    // O strip-partials -> global atomics (outO pre-zeroed)
#pragma unroll
    for (int rs = 0; rs < 2; rs++)
#pragma unroll
        for (int nt2 = 0; nt2 < 8; nt2++)
#pragma unroll
            for (int r = 0; r < 4; r++) {
                const int row = rowbase + rs * 16 + quad * 4 + r;
                atomicAdd(&outO[(size_t)row * DOUT + nt2 * 16 + ln16], o[rs][nt2][r]);
            }
}

// ---------------------------------------------------------------------------
extern "C" void kernel_launch(void* const* d_in, const int* in_sizes, int n_in,
                              void* d_out, int out_size, void* d_ws, size_t ws_size,
                              hipStream_t stream) {
    (void)in_sizes; (void)n_in; (void)out_size; (void)ws_size;

    const float* embc = (const float*)d_in[0];
    const float* embe = (const float*)d_in[1];
    const int*   mask = (const int*)d_in[2];
    const float* Wq = (const float*)d_in[3];
    const float* bq = (const float*)d_in[4];
    const float* Wk = (const float*)d_in[5];
    const float* bk = (const float*)d_in[6];
    const float* Wv = (const float*)d_in[7];
    const float* bv = (const float*)d_in[8];

    char* ws = (char*)d_ws;
    short* Qf = (short*)(ws);                        // 2 MB  frag-major, pre-scaled
    short* Kf = (short*)(ws + (2u << 20));           // 2 MB  frag-major
    short* Vf = (short*)(ws + (4u << 20));           // 2 MB  frag-major (PV B)
    float* lsum = (float*)(ws + (6u << 20));         // 32 KB
    unsigned int* bm = (unsigned int*)(ws + (8u << 20)); // 8 MB bitmap

    float* outO = (float*)d_out;                     // [8192,128]
    float* outW = outO + (size_t)NC * DOUT;          // [8192,8192]

    hipMemsetAsync(lsum, 0, NC * sizeof(float), stream);
    hipMemsetAsync(outO, 0, (size_t)NC * DOUT * sizeof(float), stream);

    pack_kernel<<<8192, 256, 0, stream>>>(mask, (u64*)bm);
    qkv_kernel<<<dim3(128, 3), 256, 0, stream>>>(embc, embe, Wq, bq, Wk, bk, Wv, bv,
                                                 Qf, Kf, Vf);
    stats_kernel<<<dim3(64, 16), 256, 0, stream>>>(bm, Qf, Kf, lsum);
    attn_kernel<<<dim3(64, 32), 256, 0, stream>>>(Qf, Kf, Vf, lsum, bm, outO, outW);
}

// Round 7
// 674.142 us; speedup vs baseline: 1.2138x; 1.0170x over previous
//
#include <hip/hip_runtime.h>

// Problem constants
#define NC   8192
#define NEFF 8192
#define DIN  256
#define DOUT 128
#define SCALE 0.08838834764831843f  // 1/sqrt(128)

typedef float  f32x4  __attribute__((ext_vector_type(4)));
typedef short  s16x8  __attribute__((ext_vector_type(8)));
typedef short  s16x4  __attribute__((ext_vector_type(4)));
typedef unsigned long long u64;

// RNE float -> bf16 (as short)
__device__ __forceinline__ short f2bf(float f) {
    unsigned int u = __builtin_bit_cast(unsigned int, f);
    u += 0x7FFFu + ((u >> 16) & 1u);
    return (short)(u >> 16);
}

__device__ __forceinline__ s16x8 ld8(const short* p) {
    return *(const s16x8*)__builtin_assume_aligned(p, 16);
}

__device__ __forceinline__ unsigned getdw(int4 v, int i) {
    switch (i & 3) {
        case 0: return (unsigned)v.x;
        case 1: return (unsigned)v.y;
        case 2: return (unsigned)v.z;
        default: return (unsigned)v.w;
    }
}

// ---------------------------------------------------------------------------
// Fragment-major layouts (all bf16, s16x8 = one lane's A/B fragment):
//  Qf[tile(512)][kc(4)][lane(64)] : Q[tile*16+ln16][kc*32+quad*8+j] * SCALE
//  Kf[tile(512)][kc(4)][lane(64)] : K[tile*16+ln16][kc*32+quad*8+j]
//  Vf[ct(64)][nt2(8)][ksub(4)][lane(64)] : V[ct*128+ksub*32+quad*8+j][nt2*16+ln16]
// bm bit layout: bit c%32 of dword bm32[row*256 + c/32]  <=>  mask[row][c]!=0
//
// ATTRIBUTION LEDGER (headline totals; per-dispatch rocprof is clock-skewed
// across runs -- R1's "attnA=269us" was anomalous, attnA is really ~170):
//  attnA 16-row non-swapped grid(128,8) b4:   ~170us  (R0 total 660)
//  attnC 32-row non-swapped grid(64,16) b3:   ~225us  (R3 total 711)
//  attnD 32-row swapped    grid(64,32) b3:    ~190us  (R4 679 / R6 686)
//  statsB (swapped) vs statsA: -7us (R4 vs R6).
// THIS ROUND: attnE = swap applied to attnA's winning 16-row geometry.
// ---------------------------------------------------------------------------

// ---------------------------------------------------------------------------
// Kernel 0: pack mask (268 MB int32) -> 8 MB bitmap. Pure streaming read,
// 8 independent loads in flight per wave, 8192 blocks (huge TLP). ~45us,
// at mask-read BW floor (~43us).
// ---------------------------------------------------------------------------
__global__ __launch_bounds__(256) void pack_kernel(
    const int* __restrict__ mask, u64* __restrict__ bm)
{
    const size_t stride = (size_t)gridDim.x * 256;     // multiple of 64
    const size_t i0 = (size_t)blockIdx.x * 256 + threadIdx.x;
    const bool lead = (threadIdx.x & 63) == 0;
    for (size_t i = i0; i < (size_t)NC * NEFF; i += 8 * stride) {
        int m[8];
#pragma unroll
        for (int j = 0; j < 8; j++) m[j] = mask[i + j * stride];
        u64 b[8];
#pragma unroll
        for (int j = 0; j < 8; j++) b[j] = __ballot(m[j] != 0);
        if (lead) {
#pragma unroll
            for (int j = 0; j < 8; j++) bm[(i + j * stride) >> 6] = b[j];
        }
    }
}

// ---------------------------------------------------------------------------
// Kernel 1: QKV projections. grid(128, 3).
// ---------------------------------------------------------------------------
__global__ __launch_bounds__(256, 2) void qkv_kernel(
    const float* __restrict__ embc, const float* __restrict__ embe,
    const float* __restrict__ Wq, const float* __restrict__ bq,
    const float* __restrict__ Wk, const float* __restrict__ bk,
    const float* __restrict__ Wv, const float* __restrict__ bv,
    short* __restrict__ Qf, short* __restrict__ Kf, short* __restrict__ Vf)
{
    const int mat = blockIdx.y;
    const float* src  = (mat == 0) ? embc : embe;
    const float* W    = (mat == 0) ? Wq : (mat == 1 ? Wk : Wv);
    const float* bias = (mat == 0) ? bq : (mat == 1 ? bk : bv);

    __shared__ short wt[DOUT][136];       // W^T staging (half-K at a time)
    __shared__ short tbuf[4][16][132];    // per-wave transpose buffer (Q/K path)
    __shared__ short tbufV[128][68];      // block-wide transpose buffer (V path)

    const int tid  = threadIdx.x;
    const int wave = tid >> 6, lane = tid & 63;
    const int quad = lane >> 4, ln16 = lane & 15;
    const int rowbase = blockIdx.x * 64;
    const int arow = rowbase + wave * 16 + ln16;   // A-fragment row

    f32x4 acc[8];
#pragma unroll
    for (int i = 0; i < 8; i++) acc[i] = (f32x4){0.f, 0.f, 0.f, 0.f};

    for (int h = 0; h < 2; h++) {
        __syncthreads();   // WAR vs previous half's reads
        {   // stage W[h*128 .. +127][0..127] transposed into wt (bf16)
            const int n0 = (tid & 31) * 4;
            const int kb = tid >> 5;               // 0..7
#pragma unroll
            for (int i = 0; i < 16; i++) {
                const int k = kb + i * 8;          // 0..127 (local)
                const float4 w4 = *(const float4*)(W + (size_t)(h * 128 + k) * DOUT + n0);
                wt[n0 + 0][k] = f2bf(w4.x);
                wt[n0 + 1][k] = f2bf(w4.y);
                wt[n0 + 2][k] = f2bf(w4.z);
                wt[n0 + 3][k] = f2bf(w4.w);
            }
        }
        __syncthreads();

        s16x8 afr[4];
#pragma unroll
        for (int kc = 0; kc < 4; kc++) {
            const float* ap = src + (size_t)arow * DIN + h * 128 + kc * 32 + quad * 8;
            const float4 a0 = *(const float4*)ap;
            const float4 a1 = *(const float4*)(ap + 4);
            s16x8 a;
            a[0] = f2bf(a0.x); a[1] = f2bf(a0.y); a[2] = f2bf(a0.z); a[3] = f2bf(a0.w);
            a[4] = f2bf(a1.x); a[5] = f2bf(a1.y); a[6] = f2bf(a1.z); a[7] = f2bf(a1.w);
            afr[kc] = a;
        }
#pragma unroll
        for (int nt = 0; nt < 8; nt++) {
#pragma unroll
            for (int kc = 0; kc < 4; kc++) {
                const s16x8 b = ld8(&wt[nt * 16 + ln16][kc * 32 + quad * 8]);
                acc[nt] = __builtin_amdgcn_mfma_f32_16x16x32_bf16(afr[kc], b, acc[nt], 0, 0, 0);
            }
        }
    }

    if (mat < 2) {
        short* dst = (mat == 0) ? Qf : Kf;
        const float sc = (mat == 0) ? SCALE : 1.0f;
        // C-layout -> tbuf (per-wave; wave-internal ordering only)
#pragma unroll
        for (int nt = 0; nt < 8; nt++) {
            const float bb = bias[nt * 16 + ln16];
#pragma unroll
            for (int r = 0; r < 4; r++)
                tbuf[wave][quad * 4 + r][nt * 16 + ln16] = f2bf((acc[nt][r] + bb) * sc);
        }
        const int tile = blockIdx.x * 4 + wave;
#pragma unroll
        for (int kc = 0; kc < 4; kc++) {
            const s16x8 fr = ld8(&tbuf[wave][ln16][kc * 32 + quad * 8]);
            *(s16x8*)(dst + ((size_t)(tile * 4 + kc) * 64 + lane) * 8) = fr;
        }
    } else {
        // V: transpose to [feat][vcol] then emit PV B-fragments
#pragma unroll
        for (int nt = 0; nt < 8; nt++) {
            const float bb = bias[nt * 16 + ln16];
#pragma unroll
            for (int r = 0; r < 4; r++)
                tbufV[nt * 16 + ln16][wave * 16 + quad * 4 + r] = f2bf(acc[nt][r] + bb);
        }
        __syncthreads();   // cross-wave reads of tbufV
        const int ct = blockIdx.x >> 1;
        const int ksub0 = (blockIdx.x & 1) * 2;
        const int ks = wave & 1;
#pragma unroll
        for (int t = 0; t < 4; t++) {
            const int nt2 = (wave >> 1) * 4 + t;
            const s16x8 fr = ld8(&tbufV[nt2 * 16 + ln16][ks * 32 + quad * 8]);
            *(s16x8*)(Vf + ((size_t)((ct * 8 + nt2) * 4 + ksub0 + ks) * 64 + lane) * 8) = fr;
        }
    }
}

// ---------------------------------------------------------------------------
// Kernel 2: per-row sum of exp(masked scores), SWAPPED layout (statsB, R4).
// grid(64, 32): blockIdx.x = 128-row block (4 waves x 32 rows),
// blockIdx.y = 256-col strip (2 iters of 128 cols). No LDS.
// R4-vs-R6 headline: -7us vs the non-swapped statsA.
// ---------------------------------------------------------------------------
__global__ __launch_bounds__(256, 5) void stats_kernel(
    const unsigned int* __restrict__ bm, const short* __restrict__ Qf,
    const short* __restrict__ Kf, float* __restrict__ lsum)
{
    const int bx = blockIdx.x, strip = blockIdx.y;
    const int tid  = threadIdx.x;
    const int wave = tid >> 6, lane = tid & 63;
    const int quad = lane >> 4, ln16 = lane & 15;
    const int rowbase = bx * 128 + wave * 32;
    const int t0 = rowbase >> 4;

    s16x8 aq[2][4];
#pragma unroll
    for (int rs = 0; rs < 2; rs++)
#pragma unroll
        for (int kc = 0; kc < 4; kc++)
            aq[rs][kc] = ld8(Qf + ((size_t)((t0 + rs) * 4 + kc) * 64 + lane) * 8);

    float lp[2] = {0.f, 0.f};

    for (int it = 0; it < 2; it++) {
        const int cb = strip * 256 + it * 128;

        int4 bmv[2];
#pragma unroll
        for (int rs = 0; rs < 2; rs++)
            bmv[rs] = *(const int4*)(bm + (size_t)(rowbase + rs * 16 + ln16) * 256 + (cb >> 5));

#pragma unroll
        for (int nt = 0; nt < 8; nt++) {
            s16x8 bq[4];
#pragma unroll
            for (int kc = 0; kc < 4; kc++)
                bq[kc] = ld8(Kf + ((size_t)(((cb >> 4) + nt) * 4 + kc) * 64 + lane) * 8);
            f32x4 c0 = (f32x4){0.f, 0.f, 0.f, 0.f};
            f32x4 c1 = (f32x4){0.f, 0.f, 0.f, 0.f};
#pragma unroll
            for (int kc = 0; kc < 4; kc++) {
                c0 = __builtin_amdgcn_mfma_f32_16x16x32_bf16(bq[kc], aq[0][kc], c0, 0, 0, 0);
                c1 = __builtin_amdgcn_mfma_f32_16x16x32_bf16(bq[kc], aq[1][kc], c1, 0, 0, 0);
            }
#pragma unroll
            for (int rs = 0; rs < 2; rs++) {
                const unsigned d = getdw(bmv[rs], nt >> 1);
#pragma unroll
                for (int r = 0; r < 4; r++) {
                    const float cv = rs ? c1[r] : c0[r];
                    if ((d >> ((nt & 1) * 16 + quad * 4 + r)) & 1u)
                        lp[rs] += __expf(cv);
                }
            }
        }
    }

    // reduce across quads (lanes with equal ln16 hold the same row)
#pragma unroll
    for (int rs = 0; rs < 2; rs++) {
        float v = lp[rs];
        v += __shfl_xor(v, 16);
        v += __shfl_xor(v, 32);
        if (quad == 0)
            atomicAdd(&lsum[rowbase + rs * 16 + ln16], v);
    }
}

// ---------------------------------------------------------------------------
// Kernel 3 (attnE): recompute S (swapped), write W, fused O = W @ V.
// attnA's WINNING geometry (16 rows/wave, grid(128,8) = 1024 blocks = exactly
// 4/CU at bounds(256,4), per-wave 16x132 LDS = 67.6KB/CU) + the swap's
// cheaper bookkeeping (int4 bm load, float4 outW store, ds_write_b64,
// scalar rl). Swap gave -35us on the 32-row shape (225->190).
// DO NOT force higher min-waves: (256,8) => VGPR=32 => 700MB spill (R2).
// ---------------------------------------------------------------------------
__global__ __launch_bounds__(256, 4) void attn_kernel(
    const short* __restrict__ Qf, const short* __restrict__ Kf,
    const short* __restrict__ Vf, const float* __restrict__ lsum,
    const unsigned int* __restrict__ bm,
    float* __restrict__ outO, float* __restrict__ outW)
{
    __shared__ short wlds[4][16][132];   // per-wave 16x128 W tile (bf16), 16.9 KB

    const int bx = blockIdx.x, strip = blockIdx.y;
    const int tid  = threadIdx.x;
    const int wave = tid >> 6, lane = tid & 63;
    const int quad = lane >> 4, ln16 = lane & 15;
    const int rowbase = bx * 64 + wave * 16;
    const int t0 = rowbase >> 4;

    s16x8 aq[4];
#pragma unroll
    for (int kc = 0; kc < 4; kc++)
        aq[kc] = ld8(Qf + ((size_t)(t0 * 4 + kc) * 64 + lane) * 8);

    const int myrow = rowbase + ln16;          // this lane's S/W row
    const float rl = 1.0f / lsum[myrow];

    f32x4 o[8];
#pragma unroll
    for (int i = 0; i < 8; i++) o[i] = (f32x4){0.f, 0.f, 0.f, 0.f};

    for (int it = 0; it < 8; it++) {
        const int cb = strip * 1024 + it * 128;

        const int4 bmv = *(const int4*)(bm + (size_t)myrow * 256 + (cb >> 5));

#pragma unroll
        for (int nt = 0; nt < 8; nt++) {
            s16x8 bq[4];
#pragma unroll
            for (int kc = 0; kc < 4; kc++)
                bq[kc] = ld8(Kf + ((size_t)(((cb >> 4) + nt) * 4 + kc) * 64 + lane) * 8);
            f32x4 c = (f32x4){0.f, 0.f, 0.f, 0.f};
#pragma unroll
            for (int kc = 0; kc < 4; kc++)
                c = __builtin_amdgcn_mfma_f32_16x16x32_bf16(bq[kc], aq[kc], c, 0, 0, 0);
            // lane: S[q = myrow][cb + nt*16 + quad*4 + r]
            const unsigned d = getdw(bmv, nt >> 1);
            float wv[4];
#pragma unroll
            for (int r = 0; r < 4; r++) {
                wv[r] = ((d >> ((nt & 1) * 16 + quad * 4 + r)) & 1u)
                            ? __expf(c[r]) * rl : 0.0f;
            }
            float4 w4; w4.x = wv[0]; w4.y = wv[1]; w4.z = wv[2]; w4.w = wv[3];
            *(float4*)(outW + (size_t)myrow * NEFF + cb + nt * 16 + quad * 4) = w4;
            s16x4 p4;
            p4[0] = f2bf(wv[0]); p4[1] = f2bf(wv[1]);
            p4[2] = f2bf(wv[2]); p4[3] = f2bf(wv[3]);
            *(s16x4*)__builtin_assume_aligned(
                &wlds[wave][ln16][nt * 16 + quad * 4], 8) = p4;
        }

        // PV: A from per-wave LDS (wave-internal ordering only; DS pipe is
        // in-order per wave and the compiler inserts the lgkmcnt waits),
        // B = Vf coalesced fragment stream. Identical to verified attnA PV.
#pragma unroll
        for (int ks = 0; ks < 4; ks++) {
            const s16x8 aw = ld8(&wlds[wave][ln16][ks * 32 + quad * 8]);
#pragma unroll
            for (int nt2 = 0; nt2 < 8; nt2++) {
                const s16x8 bv = ld8(Vf + ((size_t)(((cb >> 7) * 8 + nt2) * 4 + ks) * 64 + lane) * 8);
                o[nt2] = __builtin_amdgcn_mfma_f32_16x16x32_bf16(aw, bv, o[nt2], 0, 0, 0);
            }
        }
    }

    // O strip-partials -> global atomics (outO pre-zeroed)
#pragma unroll
    for (int nt2 = 0; nt2 < 8; nt2++)
#pragma unroll
        for (int r = 0; r < 4; r++) {
            const int row = rowbase + quad * 4 + r;
            atomicAdd(&outO[(size_t)row * DOUT + nt2 * 16 + ln16], o[nt2][r]);
        }
}

// ---------------------------------------------------------------------------
extern "C" void kernel_launch(void* const* d_in, const int* in_sizes, int n_in,
                              void* d_out, int out_size, void* d_ws, size_t ws_size,
                              hipStream_t stream) {
    (void)in_sizes; (void)n_in; (void)out_size; (void)ws_size;

    const float* embc = (const float*)d_in[0];
    const float* embe = (const float*)d_in[1];
    const int*   mask = (const int*)d_in[2];
    const float* Wq = (const float*)d_in[3];
    const float* bq = (const float*)d_in[4];
    const float* Wk = (const float*)d_in[5];
    const float* bk = (const float*)d_in[6];
    const float* Wv = (const float*)d_in[7];
    const float* bv = (const float*)d_in[8];

    char* ws = (char*)d_ws;
    short* Qf = (short*)(ws);                        // 2 MB  frag-major, pre-scaled
    short* Kf = (short*)(ws + (2u << 20));           // 2 MB  frag-major
    short* Vf = (short*)(ws + (4u << 20));           // 2 MB  frag-major (PV B)
    float* lsum = (float*)(ws + (6u << 20));         // 32 KB
    unsigned int* bm = (unsigned int*)(ws + (8u << 20)); // 8 MB bitmap

    float* outO = (float*)d_out;                     // [8192,128]
    float* outW = outO + (size_t)NC * DOUT;          // [8192,8192]

    hipMemsetAsync(lsum, 0, NC * sizeof(float), stream);
    hipMemsetAsync(outO, 0, (size_t)NC * DOUT * sizeof(float), stream);

    pack_kernel<<<8192, 256, 0, stream>>>(mask, (u64*)bm);
    qkv_kernel<<<dim3(128, 3), 256, 0, stream>>>(embc, embe, Wq, bq, Wk, bk, Wv, bv,
                                                 Qf, Kf, Vf);
    stats_kernel<<<dim3(64, 32), 256, 0, stream>>>(bm, Qf, Kf, lsum);
    attn_kernel<<<dim3(128, 8), 256, 0, stream>>>(Qf, Kf, Vf, lsum, bm, outO, outW);
}

// Round 8
// 646.754 us; speedup vs baseline: 1.2652x; 1.0423x over previous
//
#include <hip/hip_runtime.h>

// Problem constants
#define NC   8192
#define NEFF 8192
#define DIN  256
#define DOUT 128
#define SCALE 0.08838834764831843f  // 1/sqrt(128)

typedef float  f32x4  __attribute__((ext_vector_type(4)));
typedef short  s16x8  __attribute__((ext_vector_type(8)));
typedef short  s16x4  __attribute__((ext_vector_type(4)));
typedef unsigned long long u64;

// RNE float -> bf16 (as short)
__device__ __forceinline__ short f2bf(float f) {
    unsigned int u = __builtin_bit_cast(unsigned int, f);
    u += 0x7FFFu + ((u >> 16) & 1u);
    return (short)(u >> 16);
}

__device__ __forceinline__ s16x8 ld8(const short* p) {
    return *(const s16x8*)__builtin_assume_aligned(p, 16);
}

__device__ __forceinline__ unsigned getdw(int4 v, int i) {
    switch (i & 3) {
        case 0: return (unsigned)v.x;
        case 1: return (unsigned)v.y;
        case 2: return (unsigned)v.z;
        default: return (unsigned)v.w;
    }
}

// ---------------------------------------------------------------------------
// Fragment-major layouts (all bf16, s16x8 = one lane's A/B fragment):
//  Qf[tile(512)][kc(4)][lane(64)] : Q[tile*16+ln16][kc*32+quad*8+j] * SCALE
//  Kf[tile(512)][kc(4)][lane(64)] : K[tile*16+ln16][kc*32+quad*8+j]
//  Vf[ct(64)][nt2(8)][ksub(4)][lane(64)] : V[ct*128+ksub*32+quad*8+j][nt2*16+ln16]
// bm bit layout: bit c%32 of dword bm32[row*256 + c/32]  <=>  mask[row][c]!=0
//
// ATTRIBUTION LEDGER (headline totals; cross-run per-dispatch rocprof skewed):
//  attnA 16-row non-swapped (128,8) b4:  ~170us   (R0 660)
//  attnD 32-row swapped (64,32) b3:      ~190us   (R4 679 / R6 686)
//  attnE 16-row swapped (128,8) b4:      ~168us   (R7 674, VGPR 48, occ 42%)
//  harness fills: 2 x ~169us INSIDE timed window (~338us fixed).
// THIS ROUND (attnF): attnE + rotating 1-ahead prefetch in S and PV phases
// (VGPR 48 showed compiler hoisted nothing; all pipes <35% busy = L2-latency
// bound). MFMA order unchanged -> bit-identical output.
// ---------------------------------------------------------------------------

// ---------------------------------------------------------------------------
// Kernel 0: pack mask (268 MB int32) -> 8 MB bitmap. ~45us, at BW floor.
// ---------------------------------------------------------------------------
__global__ __launch_bounds__(256) void pack_kernel(
    const int* __restrict__ mask, u64* __restrict__ bm)
{
    const size_t stride = (size_t)gridDim.x * 256;     // multiple of 64
    const size_t i0 = (size_t)blockIdx.x * 256 + threadIdx.x;
    const bool lead = (threadIdx.x & 63) == 0;
    for (size_t i = i0; i < (size_t)NC * NEFF; i += 8 * stride) {
        int m[8];
#pragma unroll
        for (int j = 0; j < 8; j++) m[j] = mask[i + j * stride];
        u64 b[8];
#pragma unroll
        for (int j = 0; j < 8; j++) b[j] = __ballot(m[j] != 0);
        if (lead) {
#pragma unroll
            for (int j = 0; j < 8; j++) bm[(i + j * stride) >> 6] = b[j];
        }
    }
}

// ---------------------------------------------------------------------------
// Kernel 1: QKV projections. grid(128, 3).
// ---------------------------------------------------------------------------
__global__ __launch_bounds__(256, 2) void qkv_kernel(
    const float* __restrict__ embc, const float* __restrict__ embe,
    const float* __restrict__ Wq, const float* __restrict__ bq,
    const float* __restrict__ Wk, const float* __restrict__ bk,
    const float* __restrict__ Wv, const float* __restrict__ bv,
    short* __restrict__ Qf, short* __restrict__ Kf, short* __restrict__ Vf)
{
    const int mat = blockIdx.y;
    const float* src  = (mat == 0) ? embc : embe;
    const float* W    = (mat == 0) ? Wq : (mat == 1 ? Wk : Wv);
    const float* bias = (mat == 0) ? bq : (mat == 1 ? bk : bv);

    __shared__ short wt[DOUT][136];       // W^T staging (half-K at a time)
    __shared__ short tbuf[4][16][132];    // per-wave transpose buffer (Q/K path)
    __shared__ short tbufV[128][68];      // block-wide transpose buffer (V path)

    const int tid  = threadIdx.x;
    const int wave = tid >> 6, lane = tid & 63;
    const int quad = lane >> 4, ln16 = lane & 15;
    const int rowbase = blockIdx.x * 64;
    const int arow = rowbase + wave * 16 + ln16;   // A-fragment row

    f32x4 acc[8];
#pragma unroll
    for (int i = 0; i < 8; i++) acc[i] = (f32x4){0.f, 0.f, 0.f, 0.f};

    for (int h = 0; h < 2; h++) {
        __syncthreads();   // WAR vs previous half's reads
        {   // stage W[h*128 .. +127][0..127] transposed into wt (bf16)
            const int n0 = (tid & 31) * 4;
            const int kb = tid >> 5;               // 0..7
#pragma unroll
            for (int i = 0; i < 16; i++) {
                const int k = kb + i * 8;          // 0..127 (local)
                const float4 w4 = *(const float4*)(W + (size_t)(h * 128 + k) * DOUT + n0);
                wt[n0 + 0][k] = f2bf(w4.x);
                wt[n0 + 1][k] = f2bf(w4.y);
                wt[n0 + 2][k] = f2bf(w4.z);
                wt[n0 + 3][k] = f2bf(w4.w);
            }
        }
        __syncthreads();

        s16x8 afr[4];
#pragma unroll
        for (int kc = 0; kc < 4; kc++) {
            const float* ap = src + (size_t)arow * DIN + h * 128 + kc * 32 + quad * 8;
            const float4 a0 = *(const float4*)ap;
            const float4 a1 = *(const float4*)(ap + 4);
            s16x8 a;
            a[0] = f2bf(a0.x); a[1] = f2bf(a0.y); a[2] = f2bf(a0.z); a[3] = f2bf(a0.w);
            a[4] = f2bf(a1.x); a[5] = f2bf(a1.y); a[6] = f2bf(a1.z); a[7] = f2bf(a1.w);
            afr[kc] = a;
        }
#pragma unroll
        for (int nt = 0; nt < 8; nt++) {
#pragma unroll
            for (int kc = 0; kc < 4; kc++) {
                const s16x8 b = ld8(&wt[nt * 16 + ln16][kc * 32 + quad * 8]);
                acc[nt] = __builtin_amdgcn_mfma_f32_16x16x32_bf16(afr[kc], b, acc[nt], 0, 0, 0);
            }
        }
    }

    if (mat < 2) {
        short* dst = (mat == 0) ? Qf : Kf;
        const float sc = (mat == 0) ? SCALE : 1.0f;
        // C-layout -> tbuf (per-wave; wave-internal ordering only)
#pragma unroll
        for (int nt = 0; nt < 8; nt++) {
            const float bb = bias[nt * 16 + ln16];
#pragma unroll
            for (int r = 0; r < 4; r++)
                tbuf[wave][quad * 4 + r][nt * 16 + ln16] = f2bf((acc[nt][r] + bb) * sc);
        }
        const int tile = blockIdx.x * 4 + wave;
#pragma unroll
        for (int kc = 0; kc < 4; kc++) {
            const s16x8 fr = ld8(&tbuf[wave][ln16][kc * 32 + quad * 8]);
            *(s16x8*)(dst + ((size_t)(tile * 4 + kc) * 64 + lane) * 8) = fr;
        }
    } else {
        // V: transpose to [feat][vcol] then emit PV B-fragments
#pragma unroll
        for (int nt = 0; nt < 8; nt++) {
            const float bb = bias[nt * 16 + ln16];
#pragma unroll
            for (int r = 0; r < 4; r++)
                tbufV[nt * 16 + ln16][wave * 16 + quad * 4 + r] = f2bf(acc[nt][r] + bb);
        }
        __syncthreads();   // cross-wave reads of tbufV
        const int ct = blockIdx.x >> 1;
        const int ksub0 = (blockIdx.x & 1) * 2;
        const int ks = wave & 1;
#pragma unroll
        for (int t = 0; t < 4; t++) {
            const int nt2 = (wave >> 1) * 4 + t;
            const s16x8 fr = ld8(&tbufV[nt2 * 16 + ln16][ks * 32 + quad * 8]);
            *(s16x8*)(Vf + ((size_t)((ct * 8 + nt2) * 4 + ksub0 + ks) * 64 + lane) * 8) = fr;
        }
    }
}

// ---------------------------------------------------------------------------
// Kernel 2: per-row sum of exp(masked scores), SWAPPED layout (statsB, R4).
// grid(64, 32), bounds(256,5). UNCHANGED this round (attribution discipline).
// ---------------------------------------------------------------------------
__global__ __launch_bounds__(256, 5) void stats_kernel(
    const unsigned int* __restrict__ bm, const short* __restrict__ Qf,
    const short* __restrict__ Kf, float* __restrict__ lsum)
{
    const int bx = blockIdx.x, strip = blockIdx.y;
    const int tid  = threadIdx.x;
    const int wave = tid >> 6, lane = tid & 63;
    const int quad = lane >> 4, ln16 = lane & 15;
    const int rowbase = bx * 128 + wave * 32;
    const int t0 = rowbase >> 4;

    s16x8 aq[2][4];
#pragma unroll
    for (int rs = 0; rs < 2; rs++)
#pragma unroll
        for (int kc = 0; kc < 4; kc++)
            aq[rs][kc] = ld8(Qf + ((size_t)((t0 + rs) * 4 + kc) * 64 + lane) * 8);

    float lp[2] = {0.f, 0.f};

    for (int it = 0; it < 2; it++) {
        const int cb = strip * 256 + it * 128;

        int4 bmv[2];
#pragma unroll
        for (int rs = 0; rs < 2; rs++)
            bmv[rs] = *(const int4*)(bm + (size_t)(rowbase + rs * 16 + ln16) * 256 + (cb >> 5));

#pragma unroll
        for (int nt = 0; nt < 8; nt++) {
            s16x8 bq[4];
#pragma unroll
            for (int kc = 0; kc < 4; kc++)
                bq[kc] = ld8(Kf + ((size_t)(((cb >> 4) + nt) * 4 + kc) * 64 + lane) * 8);
            f32x4 c0 = (f32x4){0.f, 0.f, 0.f, 0.f};
            f32x4 c1 = (f32x4){0.f, 0.f, 0.f, 0.f};
#pragma unroll
            for (int kc = 0; kc < 4; kc++) {
                c0 = __builtin_amdgcn_mfma_f32_16x16x32_bf16(bq[kc], aq[0][kc], c0, 0, 0, 0);
                c1 = __builtin_amdgcn_mfma_f32_16x16x32_bf16(bq[kc], aq[1][kc], c1, 0, 0, 0);
            }
#pragma unroll
            for (int rs = 0; rs < 2; rs++) {
                const unsigned d = getdw(bmv[rs], nt >> 1);
#pragma unroll
                for (int r = 0; r < 4; r++) {
                    const float cv = rs ? c1[r] : c0[r];
                    if ((d >> ((nt & 1) * 16 + quad * 4 + r)) & 1u)
                        lp[rs] += __expf(cv);
                }
            }
        }
    }

    // reduce across quads (lanes with equal ln16 hold the same row)
#pragma unroll
    for (int rs = 0; rs < 2; rs++) {
        float v = lp[rs];
        v += __shfl_xor(v, 16);
        v += __shfl_xor(v, 32);
        if (quad == 0)
            atomicAdd(&lsum[rowbase + rs * 16 + ln16], v);
    }
}

// ---------------------------------------------------------------------------
// Kernel 3 (attnF): attnE + rotating 1-ahead prefetch.
// grid(128,8) = 1024 blocks = exactly 4/CU, bounds(256,4), 16 rows/wave.
// S phase: bqA/bqB rotation -> Kf loads stream continuously 1 nt ahead.
// PV phase: aw[4] preread (4 ds_read_b128), then flattened (ks,nt2) loop with
// bvA/bvB rotation crossing ks boundaries -> one L2-latency startup per
// phase instead of per load-group. aq reloaded per-iteration so it is dead
// during PV (register peak ~95 < 128 cap; R7 used only 48 = no hoisting).
// MFMA accumulation order identical to attnE -> bit-identical output.
// DO NOT force higher min-waves: (256,8) => VGPR=32 => 700MB spill (R2).
// ---------------------------------------------------------------------------
__global__ __launch_bounds__(256, 4) void attn_kernel(
    const short* __restrict__ Qf, const short* __restrict__ Kf,
    const short* __restrict__ Vf, const float* __restrict__ lsum,
    const unsigned int* __restrict__ bm,
    float* __restrict__ outO, float* __restrict__ outW)
{
    __shared__ short wlds[4][16][132];   // per-wave 16x128 W tile (bf16), 16.9 KB

    const int bx = blockIdx.x, strip = blockIdx.y;
    const int tid  = threadIdx.x;
    const int wave = tid >> 6, lane = tid & 63;
    const int quad = lane >> 4, ln16 = lane & 15;
    const int rowbase = bx * 64 + wave * 16;
    const int t0 = rowbase >> 4;

    const int myrow = rowbase + ln16;          // this lane's S/W row
    const float rl = 1.0f / lsum[myrow];

    f32x4 o[8];
#pragma unroll
    for (int i = 0; i < 8; i++) o[i] = (f32x4){0.f, 0.f, 0.f, 0.f};

    for (int it = 0; it < 8; it++) {
        const int cb = strip * 1024 + it * 128;

        const int4 bmv = *(const int4*)(bm + (size_t)myrow * 256 + (cb >> 5));

        // aq loaded per-iteration (L2-hot, 4 loads) so it is dead during PV.
        s16x8 aq[4];
#pragma unroll
        for (int kc = 0; kc < 4; kc++)
            aq[kc] = ld8(Qf + ((size_t)(t0 * 4 + kc) * 64 + lane) * 8);

        // ---- S phase: rotating 1-ahead Kf prefetch ----
        s16x8 bqA[4], bqB[4];
#pragma unroll
        for (int kc = 0; kc < 4; kc++)
            bqA[kc] = ld8(Kf + ((size_t)((cb >> 4) * 4 + kc) * 64 + lane) * 8);

#pragma unroll
        for (int nt = 0; nt < 8; nt++) {
            const int ntn = (nt + 1) & 7;      // wraps to 0 at nt=7 (harmless)
#pragma unroll
            for (int kc = 0; kc < 4; kc++)
                bqB[kc] = ld8(Kf + ((size_t)(((cb >> 4) + ntn) * 4 + kc) * 64 + lane) * 8);

            f32x4 c = (f32x4){0.f, 0.f, 0.f, 0.f};
#pragma unroll
            for (int kc = 0; kc < 4; kc++)
                c = __builtin_amdgcn_mfma_f32_16x16x32_bf16(bqA[kc], aq[kc], c, 0, 0, 0);

            // lane: S[q = myrow][cb + nt*16 + quad*4 + r]
            const unsigned d = getdw(bmv, nt >> 1);
            float wv[4];
#pragma unroll
            for (int r = 0; r < 4; r++) {
                wv[r] = ((d >> ((nt & 1) * 16 + quad * 4 + r)) & 1u)
                            ? __expf(c[r]) * rl : 0.0f;
            }
            float4 w4; w4.x = wv[0]; w4.y = wv[1]; w4.z = wv[2]; w4.w = wv[3];
            *(float4*)(outW + (size_t)myrow * NEFF + cb + nt * 16 + quad * 4) = w4;
            s16x4 p4;
            p4[0] = f2bf(wv[0]); p4[1] = f2bf(wv[1]);
            p4[2] = f2bf(wv[2]); p4[3] = f2bf(wv[3]);
            *(s16x4*)__builtin_assume_aligned(
                &wlds[wave][ln16][nt * 16 + quad * 4], 8) = p4;

#pragma unroll
            for (int kc = 0; kc < 4; kc++) bqA[kc] = bqB[kc];
        }

        // ---- PV phase: aw preread + rotating 1-ahead Vf prefetch ----
        // DS pipe is in-order per wave: these reads complete after the
        // ds_writes above; their latency hides under the bv load stream.
        s16x8 aw[4];
#pragma unroll
        for (int ks = 0; ks < 4; ks++)
            aw[ks] = ld8(&wlds[wave][ln16][ks * 32 + quad * 8]);

        const size_t vbase = (size_t)(cb >> 7) * 8;   // ct*8
        s16x8 bvA, bvB;
        bvA = ld8(Vf + ((vbase + 0) * 4 + 0) * 64 * 8 + (size_t)lane * 8);
#pragma unroll
        for (int j = 0; j < 32; j++) {
            const int ks  = j >> 3;            // outer (matches attnE order)
            const int nt2 = j & 7;             // inner
            const int jn  = (j + 1) & 31;      // wraps (harmless reload)
            const int ksn  = jn >> 3;
            const int nt2n = jn & 7;
            bvB = ld8(Vf + ((size_t)((vbase + nt2n) * 4 + ksn) * 64 + lane) * 8);
            o[nt2] = __builtin_amdgcn_mfma_f32_16x16x32_bf16(aw[ks], bvA, o[nt2], 0, 0, 0);
            bvA = bvB;
        }
    }

    // O strip-partials -> global atomics (outO pre-zeroed)
#pragma unroll
    for (int nt2 = 0; nt2 < 8; nt2++)
#pragma unroll
        for (int r = 0; r < 4; r++) {
            const int row = rowbase + quad * 4 + r;
            atomicAdd(&outO[(size_t)row * DOUT + nt2 * 16 + ln16], o[nt2][r]);
        }
}

// ---------------------------------------------------------------------------
extern "C" void kernel_launch(void* const* d_in, const int* in_sizes, int n_in,
                              void* d_out, int out_size, void* d_ws, size_t ws_size,
                              hipStream_t stream) {
    (void)in_sizes; (void)n_in; (void)out_size; (void)ws_size;

    const float* embc = (const float*)d_in[0];
    const float* embe = (const float*)d_in[1];
    const int*   mask = (const int*)d_in[2];
    const float* Wq = (const float*)d_in[3];
    const float* bq = (const float*)d_in[4];
    const float* Wk = (const float*)d_in[5];
    const float* bk = (const float*)d_in[6];
    const float* Wv = (const float*)d_in[7];
    const float* bv = (const float*)d_in[8];

    char* ws = (char*)d_ws;
    short* Qf = (short*)(ws);                        // 2 MB  frag-major, pre-scaled
    short* Kf = (short*)(ws + (2u << 20));           // 2 MB  frag-major
    short* Vf = (short*)(ws + (4u << 20));           // 2 MB  frag-major (PV B)
    float* lsum = (float*)(ws + (6u << 20));         // 32 KB
    unsigned int* bm = (unsigned int*)(ws + (8u << 20)); // 8 MB bitmap

    float* outO = (float*)d_out;                     // [8192,128]
    float* outW = outO + (size_t)NC * DOUT;          // [8192,8192]

    hipMemsetAsync(lsum, 0, NC * sizeof(float), stream);
    hipMemsetAsync(outO, 0, (size_t)NC * DOUT * sizeof(float), stream);

    pack_kernel<<<8192, 256, 0, stream>>>(mask, (u64*)bm);
    qkv_kernel<<<dim3(128, 3), 256, 0, stream>>>(embc, embe, Wq, bq, Wk, bk, Wv, bv,
                                                 Qf, Kf, Vf);
    stats_kernel<<<dim3(64, 32), 256, 0, stream>>>(bm, Qf, Kf, lsum);
    attn_kernel<<<dim3(128, 8), 256, 0, stream>>>(Qf, Kf, Vf, lsum, bm, outO, outW);
}